// Round 11
// baseline (49.035 us; speedup 1.0000x reference)
//
#include <hip/hip_runtime.h>

// LIF membrane update, two-dispatch split-K (partials -> finalize):
//   v_new[b,n] = ALPHA*v[b,n] + sum_i x[b,i,n]*w[i,n] - V_TH*z[b,n]
//   z_new[b,n] = (v_new[b,n] - V_TH > 0) ? 1 : 0
// Shapes: x (128,1024,512) f32, w (1024,512) f32, v,z (128,512) f32.
//
// R10 = R9 (best, 46.7us) with IG 8->16: grid 1024->2048 blocks
// (8 blocks/CU, 32 waves/CU). Occupancy ladder: 8 w/CU = 54.5, 16 w/CU =
// 46.7-49 — testing whether 32 waves/CU buys more outstanding-read depth.
// Plain x loads (R9 proved nt costs 2.2us). 2 batches/block (1w/2x),
// g=t&63 contiguous 1KB wave segments, c=t>>6 4-way i-split (16 i/thread).
// Finalize sums 16 partials in fixed order (deterministic) + LIF update.

typedef float f32x4 __attribute__((ext_vector_type(4)));

constexpr int B    = 128;
constexpr int N_IN = 1024;
constexpr int NN   = 512;
constexpr int NN4  = NN / 4;     // 128 f4 columns
constexpr int IG   = 16;         // igroups (split-K factor)
constexpr int IPG  = N_IN / IG;  // 64 i per group
constexpr int IPT  = IPG / 4;    // 16 i per thread
constexpr float ALPHA = 1.0f - 0.05f / 10.0f;  // 0.995
constexpr float V_TH  = 2.0f;

__global__ __launch_bounds__(256) void lif_partial(
    const f32x4* __restrict__ x4,
    const f32x4* __restrict__ w4,
    f32x4* __restrict__ part)   // [IG][B][2 slabs][64]
{
    const int t    = threadIdx.x;
    const int g    = t & 63;            // f4 column within slab (64 wide)
    const int c    = t >> 6;            // i-subchunk 0..3
    const int sub  = blockIdx.x & 31;   // 2 slabs x 16 igroups
    const int bp   = blockIdx.x >> 5;   // batch pair 0..63
    const int slab = sub & 1;
    const int ig   = sub >> 1;

    const int b0  = bp * 2;
    const int col = slab * 64 + g;      // f4 column 0..127
    const int i0  = ig * IPG + c * IPT;

    const f32x4* __restrict__ xp0 =
        x4 + ((size_t)b0 * N_IN + i0) * NN4 + col;
    const f32x4* __restrict__ xp1 = xp0 + (size_t)N_IN * NN4;
    const f32x4* __restrict__ wp  = w4 + (size_t)i0 * NN4 + col;

    f32x4 a0 = {0.f, 0.f, 0.f, 0.f};
    f32x4 a1 = {0.f, 0.f, 0.f, 0.f};
    #pragma unroll 8
    for (int ii = 0; ii < IPT; ++ii) {
        f32x4 wv  = wp[(size_t)ii * NN4];   // L2-hit (2MB, reused x128)
        f32x4 xv0 = xp0[(size_t)ii * NN4];  // plain load (nt costs 2.2us, R9)
        f32x4 xv1 = xp1[(size_t)ii * NN4];
        a0 += xv0 * wv;
        a1 += xv1 * wv;
    }

    __shared__ f32x4 red0[256];
    __shared__ f32x4 red1[256];
    red0[t] = a0;
    red1[t] = a1;
    __syncthreads();

    // Tree reduce over c (4 partials per column, partner stride 64 in t)
    if (t < 128) {
        red0[t] += red0[t + 128];
        red1[t] += red1[t + 128];
    }
    __syncthreads();
    if (t < 64) {
        f32x4 s0 = red0[t] + red0[t + 64];
        f32x4 s1 = red1[t] + red1[t + 64];
        const int cidx = slab * 64 + t;
        part[((size_t)ig * B + b0)     * NN4 + cidx] = s0;
        part[((size_t)ig * B + b0 + 1) * NN4 + cidx] = s1;
    }
}

__global__ __launch_bounds__(256) void lif_finalize(
    const f32x4* __restrict__ part,  // [IG][B][NN4]
    const f32x4* __restrict__ v4,
    const f32x4* __restrict__ z4,
    f32x4* __restrict__ vout4,
    f32x4* __restrict__ zout4)
{
    const int idx = blockIdx.x * 256 + threadIdx.x;   // over B*NN4 = 16384
    if (idx >= B * NN4) return;
    f32x4 s = part[idx];
    #pragma unroll
    for (int igr = 1; igr < IG; ++igr)                // fixed order: deterministic
        s += part[(size_t)igr * B * NN4 + idx];
    f32x4 vv = v4[idx];
    f32x4 zz = z4[idx];
    f32x4 vn = ALPHA * vv + s - V_TH * zz;
    vout4[idx] = vn;
    f32x4 zn;
    zn.x = (vn.x - V_TH > 0.f) ? 1.f : 0.f;
    zn.y = (vn.y - V_TH > 0.f) ? 1.f : 0.f;
    zn.z = (vn.z - V_TH > 0.f) ? 1.f : 0.f;
    zn.w = (vn.w - V_TH > 0.f) ? 1.f : 0.f;
    zout4[idx] = zn;
}

extern "C" void kernel_launch(void* const* d_in, const int* in_sizes, int n_in,
                              void* d_out, int out_size, void* d_ws, size_t ws_size,
                              hipStream_t stream) {
    const f32x4* x = (const f32x4*)d_in[0];
    const f32x4* w = (const f32x4*)d_in[1];
    const f32x4* v = (const f32x4*)d_in[2];
    const f32x4* z = (const f32x4*)d_in[3];
    f32x4* vout = (f32x4*)d_out;                 // v_new: B*NN floats
    f32x4* zout = vout + (size_t)B * NN4;        // z_new follows flat
    f32x4* part = (f32x4*)d_ws;                  // IG*B*NN4 f4 = 4 MB

    lif_partial<<<dim3(64 * 2 * IG), dim3(256), 0, stream>>>(x, w, part);
    lif_finalize<<<dim3((B * NN4 + 255) / 256), dim3(256), 0, stream>>>(
        part, v, z, vout, zout);
}

// Round 12
// 47.467 us; speedup vs baseline: 1.0330x; 1.0330x over previous
//
#include <hip/hip_runtime.h>

// LIF membrane update, two-dispatch split-K (partials -> finalize):
//   v_new[b,n] = ALPHA*v[b,n] + sum_i x[b,i,n]*w[i,n] - V_TH*z[b,n]
//   z_new[b,n] = (v_new[b,n] - V_TH > 0) ? 1 : 0
// Shapes: x (128,1024,512) f32, w (1024,512) f32, v,z (128,512) f32.
//
// FINAL = R9 (best, 46.68us ~= practical memory roofline):
//   mandatory traffic ~290 MB (x 268.4 + w 16 via 8 XCD L2s + partials 4
//   + v/z/out 1.5) / 6.3 TB/s achievable = 46.0us -> within ~1.5%.
// Swept axes: occupancy 8/16/32 w/CU = 54.5/46.7/49.0 (16 optimal);
// batches/block 1/2/4; wave-segment 256B/1KB/2KB; IG 1/8/16; 1 vs 2
// dispatches (~free); cross-block fence=683us, atomics=61us (never);
// nontemporal hint on x = +2.2us (removed).
// Structure: 1024 blocks x 256 thr (16 waves/CU), 2 batches/block (w-load
// amortized 1w/2x), g=t&63 -> contiguous 1KB wave segments, c=t>>6 4-way
// i-split (32 i/thread), IG=8. Finalize sums 8 partials in fixed order
// (deterministic) + LIF update + threshold.

typedef float f32x4 __attribute__((ext_vector_type(4)));

constexpr int B    = 128;
constexpr int N_IN = 1024;
constexpr int NN   = 512;
constexpr int NN4  = NN / 4;     // 128 f4 columns
constexpr int IG   = 8;          // igroups (split-K factor)
constexpr int IPG  = N_IN / IG;  // 128 i per group
constexpr int IPT  = IPG / 4;    // 32 i per thread
constexpr float ALPHA = 1.0f - 0.05f / 10.0f;  // 0.995
constexpr float V_TH  = 2.0f;

__global__ __launch_bounds__(256) void lif_partial(
    const f32x4* __restrict__ x4,
    const f32x4* __restrict__ w4,
    f32x4* __restrict__ part)   // [IG][B][2 slabs][64]
{
    const int t    = threadIdx.x;
    const int g    = t & 63;            // f4 column within slab (64 wide)
    const int c    = t >> 6;            // i-subchunk 0..3
    const int sub  = blockIdx.x & 15;   // 2 slabs x 8 igroups
    const int bp   = blockIdx.x >> 4;   // batch pair 0..63
    const int slab = sub & 1;
    const int ig   = sub >> 1;

    const int b0  = bp * 2;
    const int col = slab * 64 + g;      // f4 column 0..127
    const int i0  = ig * IPG + c * IPT;

    const f32x4* __restrict__ xp0 =
        x4 + ((size_t)b0 * N_IN + i0) * NN4 + col;
    const f32x4* __restrict__ xp1 = xp0 + (size_t)N_IN * NN4;
    const f32x4* __restrict__ wp  = w4 + (size_t)i0 * NN4 + col;

    f32x4 a0 = {0.f, 0.f, 0.f, 0.f};
    f32x4 a1 = {0.f, 0.f, 0.f, 0.f};
    #pragma unroll 8
    for (int ii = 0; ii < IPT; ++ii) {
        f32x4 wv  = wp[(size_t)ii * NN4];   // L2-hit (2MB, reused x128)
        f32x4 xv0 = xp0[(size_t)ii * NN4];  // plain load (nt costs 2.2us, R9)
        f32x4 xv1 = xp1[(size_t)ii * NN4];
        a0 += xv0 * wv;
        a1 += xv1 * wv;
    }

    __shared__ f32x4 red0[256];
    __shared__ f32x4 red1[256];
    red0[t] = a0;
    red1[t] = a1;
    __syncthreads();

    // Tree reduce over c (4 partials per column, partner stride 64 in t)
    if (t < 128) {
        red0[t] += red0[t + 128];
        red1[t] += red1[t + 128];
    }
    __syncthreads();
    if (t < 64) {
        f32x4 s0 = red0[t] + red0[t + 64];
        f32x4 s1 = red1[t] + red1[t + 64];
        const int cidx = slab * 64 + t;
        part[((size_t)ig * B + b0)     * NN4 + cidx] = s0;
        part[((size_t)ig * B + b0 + 1) * NN4 + cidx] = s1;
    }
}

__global__ __launch_bounds__(256) void lif_finalize(
    const f32x4* __restrict__ part,  // [IG][B][NN4]
    const f32x4* __restrict__ v4,
    const f32x4* __restrict__ z4,
    f32x4* __restrict__ vout4,
    f32x4* __restrict__ zout4)
{
    const int idx = blockIdx.x * 256 + threadIdx.x;   // over B*NN4 = 16384
    if (idx >= B * NN4) return;
    f32x4 s = part[idx];
    #pragma unroll
    for (int igr = 1; igr < IG; ++igr)                // fixed order: deterministic
        s += part[(size_t)igr * B * NN4 + idx];
    f32x4 vv = v4[idx];
    f32x4 zz = z4[idx];
    f32x4 vn = ALPHA * vv + s - V_TH * zz;
    vout4[idx] = vn;
    f32x4 zn;
    zn.x = (vn.x - V_TH > 0.f) ? 1.f : 0.f;
    zn.y = (vn.y - V_TH > 0.f) ? 1.f : 0.f;
    zn.z = (vn.z - V_TH > 0.f) ? 1.f : 0.f;
    zn.w = (vn.w - V_TH > 0.f) ? 1.f : 0.f;
    zout4[idx] = zn;
}

extern "C" void kernel_launch(void* const* d_in, const int* in_sizes, int n_in,
                              void* d_out, int out_size, void* d_ws, size_t ws_size,
                              hipStream_t stream) {
    const f32x4* x = (const f32x4*)d_in[0];
    const f32x4* w = (const f32x4*)d_in[1];
    const f32x4* v = (const f32x4*)d_in[2];
    const f32x4* z = (const f32x4*)d_in[3];
    f32x4* vout = (f32x4*)d_out;                 // v_new: B*NN floats
    f32x4* zout = vout + (size_t)B * NN4;        // z_new follows flat
    f32x4* part = (f32x4*)d_ws;                  // IG*B*NN4 f4 = 2 MB

    lif_partial<<<dim3(64 * 16), dim3(256), 0, stream>>>(x, w, part);
    lif_finalize<<<dim3((B * NN4 + 255) / 256), dim3(256), 0, stream>>>(
        part, v, z, vout, zout);
}